// Round 1
// 6819.339 us; speedup vs baseline: 2.5000x; 2.5000x over previous
//
#include <hip/hip_runtime.h>
#include <stdint.h>

// EchoStateNetwork MI355X:
//  - 64 independent sequences (b,ch); h_{t+1} = 0.9*tanh(W_in u_t(b) + W_res^T h_t) + 0.1*h_t
//  - Phase A: inp[t][b][k] = u . W_in, stashed into out[b][0][t][k] (consumed then
//    overwritten by the recurrence at exactly step t, same block, sync between).
//  - Phase B: persistent kernel, 256 blocks = 8 seq-groups x 32 col-blocks.
//    W_res column slice in VGPRs (32 float4/thread).
//    NEW (this round): fence-free exchange. h published as single-copy-atomic
//    8B pairs (value, tag=t+1) into double-buffered hbuf[t&1][seq][1024] in d_ws.
//    Consumers poll the pairs directly (relaxed agent loads) -- no flag counter,
//    no release/acquire fences, no buffer_inv L2-invalidates on the critical path.
//    ABA-safe: producer can only write slot t+2 after observing all h_{t+1},
//    which requires every consumer to have finished reading slot t.
//    Deadlock-safe: all 256 blocks co-resident (grid == #CU, launch_bounds(256,1)),
//    poll loops carry a deadman guard (wrong-answer over hang).

#define H_  1024
#define T_  1024
#define B_  16
#define CH_ 4
#define D_  64
#define F_  256   // CH*D

// ---------------- Phase A: inp GEMM (fp32, LDS tiled 64x64, K=256 in 4 chunks) ---
__global__ __launch_bounds__(256) void inp_gemm(const float* __restrict__ x,
                                                const float* __restrict__ W_in,
                                                float* __restrict__ out)
{
    __shared__ float U[64 * 68];    // [t 64][f 68]  (pad 68 -> conflict-free a reads)
    __shared__ float Wt[64 * 66];   // [f 64][k 66]  (transposed W_in tile)
    const int k0 = blockIdx.x * 64;
    const int t0 = blockIdx.y * 64;
    const int b  = blockIdx.z;
    const int tid = threadIdx.x;
    const int ty = tid >> 4, tx = tid & 15;     // 4x4 outputs per thread

    float4 acc[4];
    acc[0] = float4{0.f,0.f,0.f,0.f}; acc[1] = acc[0]; acc[2] = acc[0]; acc[3] = acc[0];

    for (int fc = 0; fc < 4; ++fc) {            // f-chunk == channel fc
        {   // stage U: thread (t_l, fs): 16 floats of x[b][fc][t0+t_l][fs*16..]
            const int t_l = tid >> 2, fs = tid & 3;
            const float* src = x + ((size_t)(b * CH_ + fc) * T_ + (t0 + t_l)) * D_ + fs * 16;
            float* dst = &U[t_l * 68 + fs * 16];
            #pragma unroll
            for (int q = 0; q < 4; ++q)
                ((float4*)dst)[q] = ((const float4*)src)[q];
        }
        {   // stage Wt (transpose): thread (k_l, fs): W_in[k0+k_l][fc*64 + fs*16..]
            const int k_l = tid >> 2, fs = tid & 3;
            const float* src = W_in + (size_t)(k0 + k_l) * F_ + fc * 64 + fs * 16;
            float4 v[4];
            #pragma unroll
            for (int q = 0; q < 4; ++q) v[q] = ((const float4*)src)[q];
            #pragma unroll
            for (int q = 0; q < 4; ++q) {
                Wt[(fs*16 + q*4 + 0) * 66 + k_l] = v[q].x;
                Wt[(fs*16 + q*4 + 1) * 66 + k_l] = v[q].y;
                Wt[(fs*16 + q*4 + 2) * 66 + k_l] = v[q].z;
                Wt[(fs*16 + q*4 + 3) * 66 + k_l] = v[q].w;
            }
        }
        __syncthreads();
        #pragma unroll 4
        for (int f4 = 0; f4 < 16; ++f4) {
            float4 a[4], bk[4];
            #pragma unroll
            for (int r = 0; r < 4; ++r)  a[r]  = *(const float4*)&U[(ty*4 + r) * 68 + f4*4];
            #pragma unroll
            for (int kk = 0; kk < 4; ++kk) bk[kk] = *(const float4*)&Wt[(f4*4 + kk) * 66 + tx*4];
            #pragma unroll
            for (int r = 0; r < 4; ++r) {
                const float4 av = a[r];
                acc[r].x = fmaf(av.x, bk[0].x, acc[r].x); acc[r].y = fmaf(av.x, bk[0].y, acc[r].y);
                acc[r].z = fmaf(av.x, bk[0].z, acc[r].z); acc[r].w = fmaf(av.x, bk[0].w, acc[r].w);
                acc[r].x = fmaf(av.y, bk[1].x, acc[r].x); acc[r].y = fmaf(av.y, bk[1].y, acc[r].y);
                acc[r].z = fmaf(av.y, bk[1].z, acc[r].z); acc[r].w = fmaf(av.y, bk[1].w, acc[r].w);
                acc[r].x = fmaf(av.z, bk[2].x, acc[r].x); acc[r].y = fmaf(av.z, bk[2].y, acc[r].y);
                acc[r].z = fmaf(av.z, bk[2].z, acc[r].z); acc[r].w = fmaf(av.z, bk[2].w, acc[r].w);
                acc[r].x = fmaf(av.w, bk[3].x, acc[r].x); acc[r].y = fmaf(av.w, bk[3].y, acc[r].y);
                acc[r].z = fmaf(av.w, bk[3].z, acc[r].z); acc[r].w = fmaf(av.w, bk[3].w, acc[r].w);
                acc[r] = acc[r];
            }
        }
        __syncthreads();
    }
    // stash inp tile into out[b][0][t0+ty*4+r][k0+tx*4..]
    #pragma unroll
    for (int r = 0; r < 4; ++r) {
        float* dst = out + ((size_t)(b * CH_) * T_ + (t0 + ty*4 + r)) * H_ + k0 + tx*4;
        *(float4*)dst = acc[r];
    }
}

// ---------------- Phase B: persistent recurrence (fence-free tagged exchange) ----
// grid 256 = group(8, low 3 bits) x colblock(32). 256 threads.
// thread: kr = tid>>3 (h-range kr*32..+32), cg = tid&7 (4 cols: C0+cg*4..)
// W regs: w4[kk] = W_res[kr*32+kk][C0+cg*4 .. +4]
// LDS smem[9216]: h skewed [s][1152] (36 floats per 32-chunk) overlaid later by
// partials [s][kr 32][33].
// hbuf layout: [2][64 seq][1024] of uint64 pairs: low32 = f32 bits, high32 = tag
// (tag stored at step t is t+1; 0 == never-written, buffer memset per launch).
__global__ __launch_bounds__(256, 1) void esn_recur(const float* __restrict__ Wres,
                                                    float* __restrict__ out,
                                                    unsigned long long* __restrict__ hbuf)
{
    __shared__ float smem[9216];
    const int bx  = blockIdx.x;
    const int grp = bx & 7;                 // seq-group: bc in [grp*8, grp*8+8)
    const int j   = bx >> 3;                // col-block
    const int C0  = j * 32;
    const int tid = threadIdx.x;
    const int kr  = tid >> 3;               // 0..31
    const int cg  = tid & 7;                // 0..7
    // epilogue / staging mapping
    const int es   = tid >> 5;              // seq-local 0..7
    const int ecol = tid & 31;              // col within 32-wide slice
    const int bc   = grp * 8 + es;
    const size_t seqBase = (size_t)bc * (T_ * H_);
    const size_t inpBase = (size_t)(bc & ~3) * (T_ * H_);   // out[b][0] stash region

    // W_res slice -> registers (one-time, L2-shared across the 8 groups)
    float4 w4[32];
    #pragma unroll
    for (int kk = 0; kk < 32; ++kk)
        w4[kk] = *(const float4*)&Wres[(size_t)(kr * 32 + kk) * H_ + C0 + cg * 4];

    for (int idx = tid; idx < 9216; idx += 256) smem[idx] = 0.f;   // h_0 = 0
    __syncthreads();

    for (int t = 0; t < T_; ++t) {
        // prefetch inp value for this thread's epilogue output (slot overwritten
        // by this block later this step -- read-before-write w/ barriers between)
        const float inp_v = out[inpBase + (size_t)t * H_ + C0 + ecol];

        if (t > 0) {
            // stage h_{t-1}: poll tagged pairs directly; no fences, no flag.
            // thread (es,ecol) round q covers col q*32+ecol -> 256B/wave coalesced.
            const unsigned long long* __restrict__ src =
                hbuf + ((size_t)(((t - 1) & 1) * 64 + bc)) * H_ + ecol;
            float* dst = &smem[es * 1152 + ecol];
            const unsigned int want = (unsigned int)t;   // tag written at step t-1
            unsigned long long v[32];
            #pragma unroll
            for (int q = 0; q < 32; ++q)
                v[q] = __hip_atomic_load(src + q * 32,
                                         __ATOMIC_RELAXED, __HIP_MEMORY_SCOPE_AGENT);
            int guard = 0;
            #pragma unroll
            for (int q = 0; q < 32; ++q) {
                while ((unsigned int)(v[q] >> 32) != want && guard < (1 << 20)) {
                    __builtin_amdgcn_s_sleep(1);
                    ++guard;                             // deadman: stale over hang
                    v[q] = __hip_atomic_load(src + q * 32,
                                             __ATOMIC_RELAXED, __HIP_MEMORY_SCOPE_AGENT);
                }
                dst[q * 36] = __uint_as_float((unsigned int)(v[q] & 0xffffffffu));
            }
        }
        __syncthreads();

        // matvec: acc[s][c] = sum_{h in kr-range} h_lds[s][h] * W[h][C0+cg*4+c]
        float4 acc4[8];
        #pragma unroll
        for (int s = 0; s < 8; ++s) acc4[s] = float4{0.f,0.f,0.f,0.f};
        const int hbase = kr * 36;
        #pragma unroll
        for (int c8 = 0; c8 < 8; ++c8) {
            const float4 wv0 = w4[c8*4+0], wv1 = w4[c8*4+1], wv2 = w4[c8*4+2], wv3 = w4[c8*4+3];
            #pragma unroll
            for (int s = 0; s < 8; ++s) {
                const float4 hv = *(const float4*)&smem[s * 1152 + hbase + c8 * 4];
                float4 a = acc4[s];
                a.x = fmaf(hv.x, wv0.x, a.x); a.y = fmaf(hv.x, wv0.y, a.y);
                a.z = fmaf(hv.x, wv0.z, a.z); a.w = fmaf(hv.x, wv0.w, a.w);
                a.x = fmaf(hv.y, wv1.x, a.x); a.y = fmaf(hv.y, wv1.y, a.y);
                a.z = fmaf(hv.y, wv1.z, a.z); a.w = fmaf(hv.y, wv1.w, a.w);
                a.x = fmaf(hv.z, wv2.x, a.x); a.y = fmaf(hv.z, wv2.y, a.y);
                a.z = fmaf(hv.z, wv2.z, a.z); a.w = fmaf(hv.z, wv2.w, a.w);
                a.x = fmaf(hv.w, wv3.x, a.x); a.y = fmaf(hv.w, wv3.y, a.y);
                a.z = fmaf(hv.w, wv3.z, a.z); a.w = fmaf(hv.w, wv3.w, a.w);
                acc4[s] = a;
            }
        }

        // old state for leak term (read BEFORE partials overlay h region)
        const float h_old = smem[es * 1152 + j * 36 + ecol];
        __syncthreads();

        // partials [s][kr][33] (+33 stride => 2-way max, free)
        #pragma unroll
        for (int s = 0; s < 8; ++s) {
            float* pp = &smem[s * 1056 + kr * 33 + cg * 4];
            pp[0] = acc4[s].x; pp[1] = acc4[s].y; pp[2] = acc4[s].z; pp[3] = acc4[s].w;
        }
        __syncthreads();

        // reduce over kr + epilogue
        float sum = 0.f;
        #pragma unroll
        for (int k2 = 0; k2 < 32; ++k2) sum += smem[es * 1056 + k2 * 33 + ecol];
        const float pre = inp_v + sum;
        const float nv  = 0.9f * tanhf(pre) + 0.1f * h_old;

        // publish tagged pair FIRST (visibility on critical path), then plain out
        const unsigned long long pv =
            ((unsigned long long)(unsigned int)(t + 1) << 32) | (unsigned long long)__float_as_uint(nv);
        __hip_atomic_store(hbuf + ((size_t)((t & 1) * 64 + bc)) * H_ + C0 + ecol, pv,
                           __ATOMIC_RELAXED, __HIP_MEMORY_SCOPE_AGENT);
        out[seqBase + (size_t)t * H_ + C0 + ecol] = nv;

        __syncthreads();   // protect LDS reuse (partials read -> next-step h stage)
    }
}

extern "C" void kernel_launch(void* const* d_in, const int* in_sizes, int n_in,
                              void* d_out, int out_size, void* d_ws, size_t ws_size,
                              hipStream_t stream) {
    const float* x    = (const float*)d_in[0];
    const float* W_in = (const float*)d_in[1];
    const float* Wres = (const float*)d_in[2];
    float* out = (float*)d_out;
    unsigned long long* hbuf = (unsigned long long*)d_ws;

    // zero tags (tag 0 == never written this launch); 2 bufs x 64 seq x 1024 x 8B = 1 MB
    hipMemsetAsync(hbuf, 0, 2ull * 64 * 1024 * sizeof(unsigned long long), stream);
    inp_gemm<<<dim3(16, 16, 16), 256, 0, stream>>>(x, W_in, out);
    esn_recur<<<dim3(256), 256, 0, stream>>>(Wres, out, hbuf);
}

// Round 2
// 6320.732 us; speedup vs baseline: 2.6972x; 1.0789x over previous
//
#include <hip/hip_runtime.h>
#include <stdint.h>

// EchoStateNetwork MI355X:
//  - 64 independent sequences (b,ch); h_{t+1} = 0.9*tanh(W_in u_t(b) + W_res^T h_t) + 0.1*h_t
//  - Phase A: inp[t][b][k] = u . W_in, stashed into out[b][0][t][k] (consumed then
//    overwritten by the recurrence at exactly step t, same block, sync between).
//  - Phase B: persistent kernel, 256 blocks = 8 seq-groups x 32 col-blocks.
//    W_res column slice in VGPRs (32 float4/thread).
//    Fence-free exchange: h published as single-copy-atomic 8B pairs
//    (value, tag=t+1) into double-buffered hbuf[t&1][seq][1024] in d_ws.
//    NEW (this round): batched retry + epilogue prefetch. The old fix-up loop
//    serialized one IF$ round trip per stale slot (~700cy x up to 31 = ~10k cy/step).
//    Now: tags checked branchlessly in registers; on any miss, ALL 32 loads are
//    re-issued as one ILP batch (one latency per round); the initial batch is
//    issued at the PREVIOUS step's epilogue so the __syncthreads vmcnt-drain
//    overlaps the load latency with the barrier.
//    ABA-safe: producer can only overwrite a slot (tag+2) after all consumers
//    of the current tag have advanced past it (their own outputs gate it).
//    Deadlock-safe: all 256 blocks co-resident (grid == #CU, launch_bounds(256,1)),
//    poll loop carries a deadman guard (wrong-answer over hang).

#define H_  1024
#define T_  1024
#define B_  16
#define CH_ 4
#define D_  64
#define F_  256   // CH*D

// ---------------- Phase A: inp GEMM (fp32, LDS tiled 64x64, K=256 in 4 chunks) ---
__global__ __launch_bounds__(256) void inp_gemm(const float* __restrict__ x,
                                                const float* __restrict__ W_in,
                                                float* __restrict__ out)
{
    __shared__ float U[64 * 68];    // [t 64][f 68]  (pad 68 -> conflict-free a reads)
    __shared__ float Wt[64 * 66];   // [f 64][k 66]  (transposed W_in tile)
    const int k0 = blockIdx.x * 64;
    const int t0 = blockIdx.y * 64;
    const int b  = blockIdx.z;
    const int tid = threadIdx.x;
    const int ty = tid >> 4, tx = tid & 15;     // 4x4 outputs per thread

    float4 acc[4];
    acc[0] = float4{0.f,0.f,0.f,0.f}; acc[1] = acc[0]; acc[2] = acc[0]; acc[3] = acc[0];

    for (int fc = 0; fc < 4; ++fc) {            // f-chunk == channel fc
        {   // stage U: thread (t_l, fs): 16 floats of x[b][fc][t0+t_l][fs*16..]
            const int t_l = tid >> 2, fs = tid & 3;
            const float* src = x + ((size_t)(b * CH_ + fc) * T_ + (t0 + t_l)) * D_ + fs * 16;
            float* dst = &U[t_l * 68 + fs * 16];
            #pragma unroll
            for (int q = 0; q < 4; ++q)
                ((float4*)dst)[q] = ((const float4*)src)[q];
        }
        {   // stage Wt (transpose): thread (k_l, fs): W_in[k0+k_l][fc*64 + fs*16..]
            const int k_l = tid >> 2, fs = tid & 3;
            const float* src = W_in + (size_t)(k0 + k_l) * F_ + fc * 64 + fs * 16;
            float4 v[4];
            #pragma unroll
            for (int q = 0; q < 4; ++q) v[q] = ((const float4*)src)[q];
            #pragma unroll
            for (int q = 0; q < 4; ++q) {
                Wt[(fs*16 + q*4 + 0) * 66 + k_l] = v[q].x;
                Wt[(fs*16 + q*4 + 1) * 66 + k_l] = v[q].y;
                Wt[(fs*16 + q*4 + 2) * 66 + k_l] = v[q].z;
                Wt[(fs*16 + q*4 + 3) * 66 + k_l] = v[q].w;
            }
        }
        __syncthreads();
        #pragma unroll 4
        for (int f4 = 0; f4 < 16; ++f4) {
            float4 a[4], bk[4];
            #pragma unroll
            for (int r = 0; r < 4; ++r)  a[r]  = *(const float4*)&U[(ty*4 + r) * 68 + f4*4];
            #pragma unroll
            for (int kk = 0; kk < 4; ++kk) bk[kk] = *(const float4*)&Wt[(f4*4 + kk) * 66 + tx*4];
            #pragma unroll
            for (int r = 0; r < 4; ++r) {
                const float4 av = a[r];
                acc[r].x = fmaf(av.x, bk[0].x, acc[r].x); acc[r].y = fmaf(av.x, bk[0].y, acc[r].y);
                acc[r].z = fmaf(av.x, bk[0].z, acc[r].z); acc[r].w = fmaf(av.x, bk[0].w, acc[r].w);
                acc[r].x = fmaf(av.y, bk[1].x, acc[r].x); acc[r].y = fmaf(av.y, bk[1].y, acc[r].y);
                acc[r].z = fmaf(av.y, bk[1].z, acc[r].z); acc[r].w = fmaf(av.y, bk[1].w, acc[r].w);
                acc[r].x = fmaf(av.z, bk[2].x, acc[r].x); acc[r].y = fmaf(av.z, bk[2].y, acc[r].y);
                acc[r].z = fmaf(av.z, bk[2].z, acc[r].z); acc[r].w = fmaf(av.z, bk[2].w, acc[r].w);
                acc[r].x = fmaf(av.w, bk[3].x, acc[r].x); acc[r].y = fmaf(av.w, bk[3].y, acc[r].y);
                acc[r].z = fmaf(av.w, bk[3].z, acc[r].z); acc[r].w = fmaf(av.w, bk[3].w, acc[r].w);
            }
        }
        __syncthreads();
    }
    // stash inp tile into out[b][0][t0+ty*4+r][k0+tx*4..]
    #pragma unroll
    for (int r = 0; r < 4; ++r) {
        float* dst = out + ((size_t)(b * CH_) * T_ + (t0 + ty*4 + r)) * H_ + k0 + tx*4;
        *(float4*)dst = acc[r];
    }
}

// ---------------- Phase B: persistent recurrence (fence-free tagged exchange) ----
// grid 256 = group(8, low 3 bits) x colblock(32). 256 threads.
// thread: kr = tid>>3 (h-range kr*32..+32), cg = tid&7 (4 cols: C0+cg*4..)
// W regs: w4[kk] = W_res[kr*32+kk][C0+cg*4 .. +4]
// LDS smem[9216]: h skewed [s][1152] (36 floats per 32-chunk) overlaid later by
// partials [s][kr 32][33].
// hbuf layout: [2][64 seq][1024] of uint64 pairs: low32 = f32 bits, high32 = tag
// (tag stored at step t is t+1; 0 == never-written, buffer memset per launch).
__global__ __launch_bounds__(256, 1) void esn_recur(const float* __restrict__ Wres,
                                                    float* __restrict__ out,
                                                    unsigned long long* __restrict__ hbuf)
{
    __shared__ float smem[9216];
    const int bx  = blockIdx.x;
    const int grp = bx & 7;                 // seq-group: bc in [grp*8, grp*8+8)
    const int j   = bx >> 3;                // col-block
    const int C0  = j * 32;
    const int tid = threadIdx.x;
    const int kr  = tid >> 3;               // 0..31
    const int cg  = tid & 7;                // 0..7
    // epilogue / staging mapping
    const int es   = tid >> 5;              // seq-local 0..7
    const int ecol = tid & 31;              // col within 32-wide slice
    const int bc   = grp * 8 + es;
    const size_t seqBase = (size_t)bc * (T_ * H_);
    const size_t inpBase = (size_t)(bc & ~3) * (T_ * H_);   // out[b][0] stash region

    // W_res slice -> registers (one-time, L2-shared across the 8 groups)
    float4 w4[32];
    #pragma unroll
    for (int kk = 0; kk < 32; ++kk)
        w4[kk] = *(const float4*)&Wres[(size_t)(kr * 32 + kk) * H_ + C0 + cg * 4];

    for (int idx = tid; idx < 9216; idx += 256) smem[idx] = 0.f;   // h_0 = 0
    __syncthreads();

    unsigned long long v[32];               // prefetched tagged pairs (64 VGPRs)

    for (int t = 0; t < T_; ++t) {
        // prefetch inp value for this thread's epilogue output (slot overwritten
        // by this block later this step -- read-before-write w/ barriers between)
        const float inp_v = out[inpBase + (size_t)t * H_ + C0 + ecol];

        if (t > 0) {
            // stage h_{t-1}: v[] was batch-issued at the previous epilogue; the
            // __syncthreads vmcnt-drain already overlapped the load latency.
            // Check tags branchlessly; on any miss, re-issue ALL 32 as one ILP
            // batch (one IF$ latency per round, not per slot). Reloading an
            // already-fresh slot is safe: its producer cannot lap until we pass.
            const unsigned long long* __restrict__ src =
                hbuf + ((size_t)(((t - 1) & 1) * 64 + bc)) * H_ + ecol;
            const unsigned int want = (unsigned int)t;   // tag written at step t-1
            int guard = 0;
            for (;;) {
                unsigned int bad = 0u;
                #pragma unroll
                for (int q = 0; q < 32; ++q)
                    bad |= ((unsigned int)(v[q] >> 32)) ^ want;
                if (!bad || ++guard > (1 << 16)) break;  // deadman: stale over hang
                __builtin_amdgcn_s_sleep(1);
                #pragma unroll
                for (int q = 0; q < 32; ++q)
                    v[q] = __hip_atomic_load(src + q * 32,
                                             __ATOMIC_RELAXED, __HIP_MEMORY_SCOPE_AGENT);
            }
            float* dst = &smem[es * 1152 + ecol];
            #pragma unroll
            for (int q = 0; q < 32; ++q)
                dst[q * 36] = __uint_as_float((unsigned int)(v[q] & 0xffffffffu));
        }
        __syncthreads();

        // matvec: acc[s][c] = sum_{h in kr-range} h_lds[s][h] * W[h][C0+cg*4+c]
        float4 acc4[8];
        #pragma unroll
        for (int s = 0; s < 8; ++s) acc4[s] = float4{0.f,0.f,0.f,0.f};
        const int hbase = kr * 36;
        #pragma unroll
        for (int c8 = 0; c8 < 8; ++c8) {
            const float4 wv0 = w4[c8*4+0], wv1 = w4[c8*4+1], wv2 = w4[c8*4+2], wv3 = w4[c8*4+3];
            #pragma unroll
            for (int s = 0; s < 8; ++s) {
                const float4 hv = *(const float4*)&smem[s * 1152 + hbase + c8 * 4];
                float4 a = acc4[s];
                a.x = fmaf(hv.x, wv0.x, a.x); a.y = fmaf(hv.x, wv0.y, a.y);
                a.z = fmaf(hv.x, wv0.z, a.z); a.w = fmaf(hv.x, wv0.w, a.w);
                a.x = fmaf(hv.y, wv1.x, a.x); a.y = fmaf(hv.y, wv1.y, a.y);
                a.z = fmaf(hv.y, wv1.z, a.z); a.w = fmaf(hv.y, wv1.w, a.w);
                a.x = fmaf(hv.z, wv2.x, a.x); a.y = fmaf(hv.z, wv2.y, a.y);
                a.z = fmaf(hv.z, wv2.z, a.z); a.w = fmaf(hv.z, wv2.w, a.w);
                a.x = fmaf(hv.w, wv3.x, a.x); a.y = fmaf(hv.w, wv3.y, a.y);
                a.z = fmaf(hv.w, wv3.z, a.z); a.w = fmaf(hv.w, wv3.w, a.w);
                acc4[s] = a;
            }
        }

        // old state for leak term (read BEFORE partials overlay h region)
        const float h_old = smem[es * 1152 + j * 36 + ecol];
        __syncthreads();

        // partials [s][kr][33] (+33 stride => 2-way max, free)
        #pragma unroll
        for (int s = 0; s < 8; ++s) {
            float* pp = &smem[s * 1056 + kr * 33 + cg * 4];
            pp[0] = acc4[s].x; pp[1] = acc4[s].y; pp[2] = acc4[s].z; pp[3] = acc4[s].w;
        }
        __syncthreads();

        // reduce over kr + epilogue
        float sum = 0.f;
        #pragma unroll
        for (int k2 = 0; k2 < 32; ++k2) sum += smem[es * 1056 + k2 * 33 + ecol];
        const float pre = inp_v + sum;
        const float nv  = 0.9f * tanhf(pre) + 0.1f * h_old;

        // publish tagged pair FIRST (visibility on critical path), then plain out
        const unsigned long long pv =
            ((unsigned long long)(unsigned int)(t + 1) << 32) | (unsigned long long)__float_as_uint(nv);
        __hip_atomic_store(hbuf + ((size_t)((t & 1) * 64 + bc)) * H_ + C0 + ecol, pv,
                           __ATOMIC_RELAXED, __HIP_MEMORY_SCOPE_AGENT);
        out[seqBase + (size_t)t * H_ + C0 + ecol] = nv;

        // prefetch next step's h batch NOW; the barrier's vmcnt(0) drain hides
        // the IF$ latency behind the group-wide re-sync.
        if (t + 1 < T_) {
            const unsigned long long* __restrict__ nsrc =
                hbuf + ((size_t)((t & 1) * 64 + bc)) * H_ + ecol;
            #pragma unroll
            for (int q = 0; q < 32; ++q)
                v[q] = __hip_atomic_load(nsrc + q * 32,
                                         __ATOMIC_RELAXED, __HIP_MEMORY_SCOPE_AGENT);
        }

        __syncthreads();   // protect LDS reuse (partials read -> next-step h stage)
    }
}

extern "C" void kernel_launch(void* const* d_in, const int* in_sizes, int n_in,
                              void* d_out, int out_size, void* d_ws, size_t ws_size,
                              hipStream_t stream) {
    const float* x    = (const float*)d_in[0];
    const float* W_in = (const float*)d_in[1];
    const float* Wres = (const float*)d_in[2];
    float* out = (float*)d_out;
    unsigned long long* hbuf = (unsigned long long*)d_ws;

    // zero tags (tag 0 == never written this launch); 2 bufs x 64 seq x 1024 x 8B = 1 MB
    hipMemsetAsync(hbuf, 0, 2ull * 64 * 1024 * sizeof(unsigned long long), stream);
    inp_gemm<<<dim3(16, 16, 16), 256, 0, stream>>>(x, W_in, out);
    esn_recur<<<dim3(256), 256, 0, stream>>>(Wres, out, hbuf);
}

// Round 3
// 4834.493 us; speedup vs baseline: 3.5264x; 1.3074x over previous
//
#include <hip/hip_runtime.h>
#include <stdint.h>

// EchoStateNetwork MI355X:
//  - 64 independent sequences (b,ch); h_{t+1} = 0.9*tanh(W_in u_t(b) + W_res^T h_t) + 0.1*h_t
//  - Phase A: inp[t][b][k] = u . W_in, stashed into out[b][0][t][k] (consumed then
//    overwritten by the recurrence at exactly step t, same block, sync between).
//  - Phase B: persistent kernel, 256 blocks = 8 seq-groups x 32 col-blocks.
//    W_res column slice in VGPRs (32 float4/thread).
//    Exchange: single-copy-atomic 8B pairs (value, tag=t+1), double-buffered
//    hbuf[t&1][seq][1024] in d_ws.
//    NEW (this round): XCD-local L2 exchange. group = bx&7 == round-robin XCD id,
//    so a group's 32 blocks share one XCD L2 (coherent for its CUs). Publish with
//    global_store_dwordx2 sc0 (L2, fast ack) and detect with a 32-wide inline-asm
//    batch of global_load_dwordx2 sc0 (L1-bypass, L2-served, ~300cy vs ~1000cy at
//    the IF$ coherence point). Safety net for undefined block->XCD mapping:
//    producers ALSO publish agent-scope, deferred one phase (drains under matvec);
//    consumers that spin out on the L2 path fall back to agent loads of the same
//    address (correct under any placement, sticky-disabled after first failure).
//    Partials get their own LDS region -> 3 barriers/step (was 4).
//    ABA-safe: producer can only overwrite a slot (tag+2) after all consumers of
//    the current tag advanced past it (their own outputs gate it).
//    Deadlock-safe: all 256 blocks co-resident (grid == #CU, launch_bounds(256,1));
//    all poll loops carry deadman guards (wrong-answer over hang).

#define H_  1024
#define T_  1024
#define B_  16
#define CH_ 4
#define D_  64
#define F_  256   // CH*D

// ---------------- Phase A: inp GEMM (fp32, LDS tiled 64x64, K=256 in 4 chunks) ---
__global__ __launch_bounds__(256) void inp_gemm(const float* __restrict__ x,
                                                const float* __restrict__ W_in,
                                                float* __restrict__ out)
{
    __shared__ float U[64 * 68];    // [t 64][f 68]  (pad 68 -> conflict-free a reads)
    __shared__ float Wt[64 * 66];   // [f 64][k 66]  (transposed W_in tile)
    const int k0 = blockIdx.x * 64;
    const int t0 = blockIdx.y * 64;
    const int b  = blockIdx.z;
    const int tid = threadIdx.x;
    const int ty = tid >> 4, tx = tid & 15;     // 4x4 outputs per thread

    float4 acc[4];
    acc[0] = float4{0.f,0.f,0.f,0.f}; acc[1] = acc[0]; acc[2] = acc[0]; acc[3] = acc[0];

    for (int fc = 0; fc < 4; ++fc) {            // f-chunk == channel fc
        {   // stage U: thread (t_l, fs): 16 floats of x[b][fc][t0+t_l][fs*16..]
            const int t_l = tid >> 2, fs = tid & 3;
            const float* src = x + ((size_t)(b * CH_ + fc) * T_ + (t0 + t_l)) * D_ + fs * 16;
            float* dst = &U[t_l * 68 + fs * 16];
            #pragma unroll
            for (int q = 0; q < 4; ++q)
                ((float4*)dst)[q] = ((const float4*)src)[q];
        }
        {   // stage Wt (transpose): thread (k_l, fs): W_in[k0+k_l][fc*64 + fs*16..]
            const int k_l = tid >> 2, fs = tid & 3;
            const float* src = W_in + (size_t)(k0 + k_l) * F_ + fc * 64 + fs * 16;
            float4 v[4];
            #pragma unroll
            for (int q = 0; q < 4; ++q) v[q] = ((const float4*)src)[q];
            #pragma unroll
            for (int q = 0; q < 4; ++q) {
                Wt[(fs*16 + q*4 + 0) * 66 + k_l] = v[q].x;
                Wt[(fs*16 + q*4 + 1) * 66 + k_l] = v[q].y;
                Wt[(fs*16 + q*4 + 2) * 66 + k_l] = v[q].z;
                Wt[(fs*16 + q*4 + 3) * 66 + k_l] = v[q].w;
            }
        }
        __syncthreads();
        #pragma unroll 4
        for (int f4 = 0; f4 < 16; ++f4) {
            float4 a[4], bk[4];
            #pragma unroll
            for (int r = 0; r < 4; ++r)  a[r]  = *(const float4*)&U[(ty*4 + r) * 68 + f4*4];
            #pragma unroll
            for (int kk = 0; kk < 4; ++kk) bk[kk] = *(const float4*)&Wt[(f4*4 + kk) * 66 + tx*4];
            #pragma unroll
            for (int r = 0; r < 4; ++r) {
                const float4 av = a[r];
                acc[r].x = fmaf(av.x, bk[0].x, acc[r].x); acc[r].y = fmaf(av.x, bk[0].y, acc[r].y);
                acc[r].z = fmaf(av.x, bk[0].z, acc[r].z); acc[r].w = fmaf(av.x, bk[0].w, acc[r].w);
                acc[r].x = fmaf(av.y, bk[1].x, acc[r].x); acc[r].y = fmaf(av.y, bk[1].y, acc[r].y);
                acc[r].z = fmaf(av.y, bk[1].z, acc[r].z); acc[r].w = fmaf(av.y, bk[1].w, acc[r].w);
                acc[r].x = fmaf(av.z, bk[2].x, acc[r].x); acc[r].y = fmaf(av.z, bk[2].y, acc[r].y);
                acc[r].z = fmaf(av.z, bk[2].z, acc[r].z); acc[r].w = fmaf(av.z, bk[2].w, acc[r].w);
                acc[r].x = fmaf(av.w, bk[3].x, acc[r].x); acc[r].y = fmaf(av.w, bk[3].y, acc[r].y);
                acc[r].z = fmaf(av.w, bk[3].z, acc[r].z); acc[r].w = fmaf(av.w, bk[3].w, acc[r].w);
            }
        }
        __syncthreads();
    }
    // stash inp tile into out[b][0][t0+ty*4+r][k0+tx*4..]
    #pragma unroll
    for (int r = 0; r < 4; ++r) {
        float* dst = out + ((size_t)(b * CH_) * T_ + (t0 + ty*4 + r)) * H_ + k0 + tx*4;
        *(float4*)dst = acc[r];
    }
}

// 32x global_load_dwordx2 sc0 (L1-bypass, XCD-L2 served) + vmcnt(0), one batch.
// Offsets 0..3840 from two bases (13-bit imm limit); outputs early-clobber so the
// allocator can't alias them onto the live address pairs.
#define LOAD32_SC0(v, a0, a1)                                                     \
    asm volatile(                                                                 \
        "global_load_dwordx2 %0, %32, off sc0\n\t"                                \
        "global_load_dwordx2 %1, %32, off offset:256 sc0\n\t"                     \
        "global_load_dwordx2 %2, %32, off offset:512 sc0\n\t"                     \
        "global_load_dwordx2 %3, %32, off offset:768 sc0\n\t"                     \
        "global_load_dwordx2 %4, %32, off offset:1024 sc0\n\t"                    \
        "global_load_dwordx2 %5, %32, off offset:1280 sc0\n\t"                    \
        "global_load_dwordx2 %6, %32, off offset:1536 sc0\n\t"                    \
        "global_load_dwordx2 %7, %32, off offset:1792 sc0\n\t"                    \
        "global_load_dwordx2 %8, %32, off offset:2048 sc0\n\t"                    \
        "global_load_dwordx2 %9, %32, off offset:2304 sc0\n\t"                    \
        "global_load_dwordx2 %10, %32, off offset:2560 sc0\n\t"                   \
        "global_load_dwordx2 %11, %32, off offset:2816 sc0\n\t"                   \
        "global_load_dwordx2 %12, %32, off offset:3072 sc0\n\t"                   \
        "global_load_dwordx2 %13, %32, off offset:3328 sc0\n\t"                   \
        "global_load_dwordx2 %14, %32, off offset:3584 sc0\n\t"                   \
        "global_load_dwordx2 %15, %32, off offset:3840 sc0\n\t"                   \
        "global_load_dwordx2 %16, %33, off sc0\n\t"                               \
        "global_load_dwordx2 %17, %33, off offset:256 sc0\n\t"                    \
        "global_load_dwordx2 %18, %33, off offset:512 sc0\n\t"                    \
        "global_load_dwordx2 %19, %33, off offset:768 sc0\n\t"                    \
        "global_load_dwordx2 %20, %33, off offset:1024 sc0\n\t"                   \
        "global_load_dwordx2 %21, %33, off offset:1280 sc0\n\t"                   \
        "global_load_dwordx2 %22, %33, off offset:1536 sc0\n\t"                   \
        "global_load_dwordx2 %23, %33, off offset:1792 sc0\n\t"                   \
        "global_load_dwordx2 %24, %33, off offset:2048 sc0\n\t"                   \
        "global_load_dwordx2 %25, %33, off offset:2304 sc0\n\t"                   \
        "global_load_dwordx2 %26, %33, off offset:2560 sc0\n\t"                   \
        "global_load_dwordx2 %27, %33, off offset:2816 sc0\n\t"                   \
        "global_load_dwordx2 %28, %33, off offset:3072 sc0\n\t"                   \
        "global_load_dwordx2 %29, %33, off offset:3328 sc0\n\t"                   \
        "global_load_dwordx2 %30, %33, off offset:3584 sc0\n\t"                   \
        "global_load_dwordx2 %31, %33, off offset:3840 sc0\n\t"                   \
        "s_waitcnt vmcnt(0)"                                                      \
        : "=&v"(v[0]),  "=&v"(v[1]),  "=&v"(v[2]),  "=&v"(v[3]),                  \
          "=&v"(v[4]),  "=&v"(v[5]),  "=&v"(v[6]),  "=&v"(v[7]),                  \
          "=&v"(v[8]),  "=&v"(v[9]),  "=&v"(v[10]), "=&v"(v[11]),                 \
          "=&v"(v[12]), "=&v"(v[13]), "=&v"(v[14]), "=&v"(v[15]),                 \
          "=&v"(v[16]), "=&v"(v[17]), "=&v"(v[18]), "=&v"(v[19]),                 \
          "=&v"(v[20]), "=&v"(v[21]), "=&v"(v[22]), "=&v"(v[23]),                 \
          "=&v"(v[24]), "=&v"(v[25]), "=&v"(v[26]), "=&v"(v[27]),                 \
          "=&v"(v[28]), "=&v"(v[29]), "=&v"(v[30]), "=&v"(v[31])                  \
        : "v"(a0), "v"(a1)                                                        \
        : "memory")

// ---------------- Phase B: persistent recurrence (XCD-L2 tagged exchange) -------
// grid 256 = group(8, low 3 bits = XCD round-robin) x colblock(32). 256 threads.
// thread: kr = tid>>3 (h-range kr*32..+32), cg = tid&7 (4 cols: C0+cg*4..)
// LDS: [0,9216) h skewed [s][1152] (36 floats per 32-chunk);
//      [9216,17664) partials [s][kr 32][33] (own region -> h stays intact all step).
// hbuf layout: [2][64 seq][1024] u64 pairs: low32 = f32 bits, high32 = tag
// (tag stored at step t is t+1; 0 == never-written, memset per launch).
__global__ __launch_bounds__(256, 1) void esn_recur(const float* __restrict__ Wres,
                                                    float* __restrict__ out,
                                                    unsigned long long* __restrict__ hbuf)
{
    __shared__ float smem[17664];
    const int bx  = blockIdx.x;
    const int grp = bx & 7;                 // seq-group == XCD id under round-robin
    const int j   = bx >> 3;                // col-block
    const int C0  = j * 32;
    const int tid = threadIdx.x;
    const int kr  = tid >> 3;               // 0..31
    const int cg  = tid & 7;                // 0..7
    const int es   = tid >> 5;              // seq-local 0..7
    const int ecol = tid & 31;              // col within 32-wide slice
    const int bc   = grp * 8 + es;
    const size_t seqBase = (size_t)bc * (T_ * H_);
    const size_t inpBase = (size_t)(bc & ~3) * (T_ * H_);   // out[b][0] stash region

    // W_res slice -> registers (one-time, L2-shared across the 8 groups)
    float4 w4[32];
    #pragma unroll
    for (int kk = 0; kk < 32; ++kk)
        w4[kk] = *(const float4*)&Wres[(size_t)(kr * 32 + kk) * H_ + C0 + cg * 4];

    for (int idx = tid; idx < 17664; idx += 256) smem[idx] = 0.f;   // h_0 = 0
    __syncthreads();

    int use_fast = 1;                                // sticky L2-path enable
    unsigned long long  pend_pv   = 0;               // deferred agent publish
    unsigned long long* pend_addr = nullptr;

    for (int t = 0; t < T_; ++t) {
        float inp_v;
        // ---- phase 1: detect + stage h_{t-1} ------------------------------
        if (t > 0) {
            unsigned long long v[32];
            const unsigned long long* src =
                hbuf + ((size_t)(((t - 1) & 1) * 64 + bc)) * H_ + ecol;
            const unsigned long long a0 = (unsigned long long)src;
            const unsigned long long a1 = a0 + 4096;
            const unsigned int want = (unsigned int)t;   // tag written at step t-1
            unsigned int bad = 1u;
            if (use_fast) {
                int spins = 0;
                for (;;) {
                    LOAD32_SC0(v, a0, a1);
                    bad = 0u;
                    #pragma unroll
                    for (int q = 0; q < 32; ++q)
                        bad |= ((unsigned int)(v[q] >> 32)) ^ want;
                    if (!bad) break;
                    if (++spins >= 64) break;        // bounded: fall back, stay correct
                    __builtin_amdgcn_s_sleep(1);
                }
                if (bad) use_fast = 0;               // mapping not XCD-local: go agent
            }
            if (bad) {                               // agent-scope fallback (mall)
                int guard = 0;
                for (;;) {
                    #pragma unroll
                    for (int q = 0; q < 32; ++q)
                        v[q] = __hip_atomic_load(src + q * 32,
                                                 __ATOMIC_RELAXED, __HIP_MEMORY_SCOPE_AGENT);
                    unsigned int b2 = 0u;
                    #pragma unroll
                    for (int q = 0; q < 32; ++q)
                        b2 |= ((unsigned int)(v[q] >> 32)) ^ want;
                    if (!b2 || ++guard > (1 << 16)) break;   // deadman: stale over hang
                    __builtin_amdgcn_s_sleep(2);
                }
            }
            inp_v = out[inpBase + (size_t)t * H_ + C0 + ecol];  // same-block slot (see top)
            float* dst = &smem[es * 1152 + ecol];
            #pragma unroll
            for (int q = 0; q < 32; ++q)
                dst[q * 36] = __uint_as_float((unsigned int)(v[q] & 0xffffffffu));
        } else {
            inp_v = out[inpBase + C0 + ecol];
        }
        __syncthreads();   // bar1: h staged

        // deferred agent publish of h_{t-1}: slow mall ack drains under matvec
        if (t > 0)
            __hip_atomic_store(pend_addr, pend_pv,
                               __ATOMIC_RELAXED, __HIP_MEMORY_SCOPE_AGENT);

        // ---- phase 2: matvec ---------------------------------------------
        float4 acc4[8];
        #pragma unroll
        for (int s = 0; s < 8; ++s) acc4[s] = float4{0.f,0.f,0.f,0.f};
        const int hbase = kr * 36;
        #pragma unroll
        for (int c8 = 0; c8 < 8; ++c8) {
            const float4 wv0 = w4[c8*4+0], wv1 = w4[c8*4+1], wv2 = w4[c8*4+2], wv3 = w4[c8*4+3];
            #pragma unroll
            for (int s = 0; s < 8; ++s) {
                const float4 hv = *(const float4*)&smem[s * 1152 + hbase + c8 * 4];
                float4 a = acc4[s];
                a.x = fmaf(hv.x, wv0.x, a.x); a.y = fmaf(hv.x, wv0.y, a.y);
                a.z = fmaf(hv.x, wv0.z, a.z); a.w = fmaf(hv.x, wv0.w, a.w);
                a.x = fmaf(hv.y, wv1.x, a.x); a.y = fmaf(hv.y, wv1.y, a.y);
                a.z = fmaf(hv.y, wv1.z, a.z); a.w = fmaf(hv.y, wv1.w, a.w);
                a.x = fmaf(hv.z, wv2.x, a.x); a.y = fmaf(hv.z, wv2.y, a.y);
                a.z = fmaf(hv.z, wv2.z, a.z); a.w = fmaf(hv.z, wv2.w, a.w);
                a.x = fmaf(hv.w, wv3.x, a.x); a.y = fmaf(hv.w, wv3.y, a.y);
                a.z = fmaf(hv.w, wv3.z, a.z); a.w = fmaf(hv.w, wv3.w, a.w);
                acc4[s] = a;
            }
        }
        // partials into their own LDS region (+33 stride => 2-way max, free)
        #pragma unroll
        for (int s = 0; s < 8; ++s) {
            float* pp = &smem[9216 + s * 1056 + kr * 33 + cg * 4];
            pp[0] = acc4[s].x; pp[1] = acc4[s].y; pp[2] = acc4[s].z; pp[3] = acc4[s].w;
        }
        __syncthreads();   // bar2: partials visible

        // ---- phase 3: reduce + epilogue + publish -------------------------
        float s0 = 0.f, s1 = 0.f, s2 = 0.f, s3 = 0.f;
        #pragma unroll
        for (int k2 = 0; k2 < 32; k2 += 4) {
            s0 += smem[9216 + es * 1056 + (k2+0) * 33 + ecol];
            s1 += smem[9216 + es * 1056 + (k2+1) * 33 + ecol];
            s2 += smem[9216 + es * 1056 + (k2+2) * 33 + ecol];
            s3 += smem[9216 + es * 1056 + (k2+3) * 33 + ecol];
        }
        const float sum   = (s0 + s1) + (s2 + s3);
        const float h_old = smem[es * 1152 + j * 36 + ecol];   // h region intact
        const float pre = inp_v + sum;
        const float nv  = 0.9f * tanhf(pre) + 0.1f * h_old;

        unsigned long long* paddr = hbuf + ((size_t)((t & 1) * 64 + bc)) * H_ + C0 + ecol;
        const unsigned long long pv =
            ((unsigned long long)(unsigned int)(t + 1) << 32)
            | (unsigned long long)__float_as_uint(nv);
        // fast publish: XCD-L2 (sc0), quick ack -> cheap bar3 drain
        asm volatile("global_store_dwordx2 %0, %1, off sc0"
                     :: "v"((unsigned long long)paddr), "v"(pv) : "memory");
        out[seqBase + (size_t)t * H_ + C0 + ecol] = nv;
        pend_pv = pv; pend_addr = paddr;             // agent copy goes out next phase 2

        __syncthreads();   // bar3: h region may be overwritten next step
    }
}

extern "C" void kernel_launch(void* const* d_in, const int* in_sizes, int n_in,
                              void* d_out, int out_size, void* d_ws, size_t ws_size,
                              hipStream_t stream) {
    const float* x    = (const float*)d_in[0];
    const float* W_in = (const float*)d_in[1];
    const float* Wres = (const float*)d_in[2];
    float* out = (float*)d_out;
    unsigned long long* hbuf = (unsigned long long*)d_ws;

    // zero tags (tag 0 == never written this launch); 2 bufs x 64 seq x 1024 x 8B = 1 MB
    hipMemsetAsync(hbuf, 0, 2ull * 64 * 1024 * sizeof(unsigned long long), stream);
    inp_gemm<<<dim3(16, 16, 16), 256, 0, stream>>>(x, W_in, out);
    esn_recur<<<dim3(256), 256, 0, stream>>>(Wres, out, hbuf);
}